// Round 5
// baseline (1046.814 us; speedup 1.0000x reference)
//
#include <hip/hip_runtime.h>
#include <math.h>
#include <stdint.h>

#define ZDIM   512
#define MDIM   512
#define HHN    511
#define NBATCH 65536

typedef float f32x4 __attribute__((ext_vector_type(4)));
typedef short s16x8 __attribute__((ext_vector_type(8)));

// float -> bf16 (round-to-nearest-even), returns low 16 bits
__device__ __forceinline__ uint32_t bf16rne(float x) {
    uint32_t u = __float_as_uint(x);
    return (u + 0x7fffu + ((u >> 16) & 1u)) >> 16;
}
// split x into hi+lo bf16 (x ~= hi + lo, |err| <~ 2^-18 |x|)
__device__ __forceinline__ void split2(float x, short& h, short& l) {
    uint32_t hu = bf16rne(x);
    float hf = __uint_as_float(hu << 16);
    uint32_t lu = bf16rne(x - hf);
    h = (short)hu; l = (short)lu;
}

// ---------------------------------------------------------------------------
// K1: normalize v rows -> vn (row 511 zeroed); rrii[m] = Rs[m,m]*r2diag[m]
// ---------------------------------------------------------------------------
__global__ void __launch_bounds__(64) prep_kernel(const float* __restrict__ v,
                                                  const float* __restrict__ Rs,
                                                  const float* __restrict__ r2diag,
                                                  float* __restrict__ vn,
                                                  float* __restrict__ rrii) {
    int b    = blockIdx.x;
    int lane = threadIdx.x;  // 64
    if (b < HHN) {
        const float4* src = reinterpret_cast<const float4*>(v + (size_t)b * ZDIM);
        float4 a0 = src[lane * 2];
        float4 a1 = src[lane * 2 + 1];
        float s = a0.x*a0.x + a0.y*a0.y + a0.z*a0.z + a0.w*a0.w
                + a1.x*a1.x + a1.y*a1.y + a1.z*a1.z + a1.w*a1.w;
#pragma unroll
        for (int off = 32; off >= 1; off >>= 1) s += __shfl_xor(s, off, 64);
        float inv = 1.0f / sqrtf(s);
        float4 o0 = make_float4(a0.x*inv, a0.y*inv, a0.z*inv, a0.w*inv);
        float4 o1 = make_float4(a1.x*inv, a1.y*inv, a1.z*inv, a1.w*inv);
        float4* dst = reinterpret_cast<float4*>(vn + (size_t)b * ZDIM);
        dst[lane * 2]     = o0;
        dst[lane * 2 + 1] = o1;
    } else {
        for (int m = lane; m < MDIM; m += 64)
            rrii[m] = Rs[(size_t)m * MDIM + m] * r2diag[m];
        // zero pad-row 511 of vn so all 512-wide ops are safe
        float4 z4 = make_float4(0.f, 0.f, 0.f, 0.f);
        float4* dst = reinterpret_cast<float4*>(vn + (size_t)HHN * ZDIM);
        dst[lane * 2]     = z4;
        dst[lane * 2 + 1] = z4;
    }
}

// ---------------------------------------------------------------------------
// K2a: G = vn @ vn^T (512x512, K=512). fp32 VALU tiled NT-GEMM.
// ---------------------------------------------------------------------------
__global__ void __launch_bounds__(256) gram_kernel(const float* __restrict__ vn,
                                                   float* __restrict__ G) {
    int i0 = blockIdx.y * 64;
    int j0 = blockIdx.x * 64;
    int tid = threadIdx.x;
    int tx = tid & 15, ty = tid >> 4;

    __shared__ float Ai[16][68];
    __shared__ float Bj[16][68];

    float acc[4][4] = {};
    for (int k0 = 0; k0 < ZDIM; k0 += 16) {
        {
            int r = tid >> 2, c4 = tid & 3;
            float4 g = *reinterpret_cast<const float4*>(vn + (size_t)(i0 + r) * ZDIM + k0 + c4 * 4);
            Ai[c4*4+0][r] = g.x; Ai[c4*4+1][r] = g.y; Ai[c4*4+2][r] = g.z; Ai[c4*4+3][r] = g.w;
        }
        {
            int r = tid >> 2, c4 = tid & 3;
            float4 g = *reinterpret_cast<const float4*>(vn + (size_t)(j0 + r) * ZDIM + k0 + c4 * 4);
            Bj[c4*4+0][r] = g.x; Bj[c4*4+1][r] = g.y; Bj[c4*4+2][r] = g.z; Bj[c4*4+3][r] = g.w;
        }
        __syncthreads();
#pragma unroll
        for (int kk = 0; kk < 16; ++kk) {
            float4 a4 = *reinterpret_cast<const float4*>(&Ai[kk][ty * 4]);
            float4 b4 = *reinterpret_cast<const float4*>(&Bj[kk][tx * 4]);
            float av[4] = {a4.x, a4.y, a4.z, a4.w};
            float bv[4] = {b4.x, b4.y, b4.z, b4.w};
#pragma unroll
            for (int i = 0; i < 4; ++i)
#pragma unroll
                for (int j = 0; j < 4; ++j)
                    acc[i][j] = fmaf(av[i], bv[j], acc[i][j]);
        }
        __syncthreads();
    }
#pragma unroll
    for (int i = 0; i < 4; ++i)
#pragma unroll
        for (int j = 0; j < 4; ++j)
            G[(size_t)(i0 + ty * 4 + i) * ZDIM + j0 + tx * 4 + j] = acc[i][j];
}

// ---------------------------------------------------------------------------
// K2b: left-looking partial for column-block b:
//   D[r][j] = vn[j][r] - 2 * sum_{i<64b} D[r][i] * G[i][j],  j in [64b,64b+64)
// grid = 8 row-tiles x 256 thr. (b=0: pure transpose init.)
// ---------------------------------------------------------------------------
__global__ void __launch_bounds__(256) partial_kernel(float* __restrict__ D,
                                                      const float* __restrict__ G,
                                                      const float* __restrict__ vn,
                                                      int b) {
    int r0 = blockIdx.x * 64;
    int c0 = b * 64;
    int K  = c0;
    int tid = threadIdx.x;
    int tx = tid & 15, ty = tid >> 4;

    __shared__ float As[16][68];   // D[k][r] transposed
    __shared__ float Bs[16][68];   // G[k][c]

    float acc[4][4] = {};
    for (int k0 = 0; k0 < K; k0 += 16) {
        {
            int r = tid >> 2, c4 = tid & 3;
            float4 g = *reinterpret_cast<const float4*>(D + (size_t)(r0 + r) * ZDIM + k0 + c4 * 4);
            As[c4*4+0][r] = g.x; As[c4*4+1][r] = g.y; As[c4*4+2][r] = g.z; As[c4*4+3][r] = g.w;
        }
        {
            int kk = tid >> 4, c4 = tid & 15;
            float4 g = *reinterpret_cast<const float4*>(G + (size_t)(k0 + kk) * ZDIM + c0 + c4 * 4);
            *reinterpret_cast<float4*>(&Bs[kk][c4 * 4]) = g;
        }
        __syncthreads();
#pragma unroll
        for (int kk = 0; kk < 16; ++kk) {
            float4 a4 = *reinterpret_cast<const float4*>(&As[kk][ty * 4]);
            float4 b4 = *reinterpret_cast<const float4*>(&Bs[kk][tx * 4]);
            float av[4] = {a4.x, a4.y, a4.z, a4.w};
            float bv[4] = {b4.x, b4.y, b4.z, b4.w};
#pragma unroll
            for (int i = 0; i < 4; ++i)
#pragma unroll
                for (int j = 0; j < 4; ++j)
                    acc[i][j] = fmaf(av[i], bv[j], acc[i][j]);
        }
        __syncthreads();
    }
#pragma unroll
    for (int i = 0; i < 4; ++i) {
        int rg = r0 + ty * 4 + i;
#pragma unroll
        for (int j = 0; j < 4; ++j) {
            int cg = c0 + tx * 4 + j;
            D[(size_t)rg * ZDIM + cg] = vn[(size_t)cg * ZDIM + rg] - 2.0f * acc[i][j];
        }
    }
}

// ---------------------------------------------------------------------------
// K2c: in-block forward substitution for column-block b (64 cols):
//   for j asc: D[r][j] -= 2 * sum_{i<j in blk} D[r][i] * G[i][j]
// 1 block x 512 threads; thread = row r; fully-unrolled register sweep,
// no cross-lane ops. G-block (pre-scaled by -2) broadcast from LDS.
// ---------------------------------------------------------------------------
__global__ void __launch_bounds__(512) trisolve_kernel(float* __restrict__ D,
                                                       const float* __restrict__ G,
                                                       int b) {
    __shared__ float Gs[64][65];   // -2 * G[blk][blk]
    int tid = threadIdx.x;
    int c0 = b * 64;
    {
        int i = tid >> 3, j8 = (tid & 7) * 8;
        const float* gp = G + (size_t)(c0 + i) * ZDIM + c0 + j8;
        float4 g0 = *reinterpret_cast<const float4*>(gp);
        float4 g1 = *reinterpret_cast<const float4*>(gp + 4);
        Gs[i][j8+0] = -2.0f*g0.x; Gs[i][j8+1] = -2.0f*g0.y;
        Gs[i][j8+2] = -2.0f*g0.z; Gs[i][j8+3] = -2.0f*g0.w;
        Gs[i][j8+4] = -2.0f*g1.x; Gs[i][j8+5] = -2.0f*g1.y;
        Gs[i][j8+6] = -2.0f*g1.z; Gs[i][j8+7] = -2.0f*g1.w;
    }
    __syncthreads();

    float dl[64];
    float* drow = D + (size_t)tid * ZDIM + c0;
#pragma unroll
    for (int q = 0; q < 16; ++q) {
        float4 t = *reinterpret_cast<const float4*>(drow + q * 4);
        dl[q*4+0] = t.x; dl[q*4+1] = t.y; dl[q*4+2] = t.z; dl[q*4+3] = t.w;
    }
#pragma unroll
    for (int j = 0; j < 64; ++j) {
        float acc = dl[j];
#pragma unroll
        for (int i = 0; i < j; ++i)
            acc = fmaf(dl[i], Gs[i][j], acc);
        dl[j] = acc;
    }
#pragma unroll
    for (int q = 0; q < 16; ++q) {
        float4 t = make_float4(dl[q*4+0], dl[q*4+1], dl[q*4+2], dl[q*4+3]);
        *reinterpret_cast<float4*>(drow + q * 4) = t;
    }
}

// ---------------------------------------------------------------------------
// K2d: Q = I - 2 * D @ vn   (512x512x512 NN GEMM, fp32 VALU)
// ---------------------------------------------------------------------------
__global__ void __launch_bounds__(256) qbuild_kernel(const float* __restrict__ D,
                                                     const float* __restrict__ vn,
                                                     float* __restrict__ Q) {
    int r0 = blockIdx.y * 64;
    int c0 = blockIdx.x * 64;
    int tid = threadIdx.x;
    int tx = tid & 15, ty = tid >> 4;

    __shared__ float As[16][68];   // D[k][r] transposed
    __shared__ float Bs[16][68];   // vn[k][c]

    float acc[4][4] = {};
    for (int k0 = 0; k0 < ZDIM; k0 += 16) {
        {
            int r = tid >> 2, c4 = tid & 3;
            float4 g = *reinterpret_cast<const float4*>(D + (size_t)(r0 + r) * ZDIM + k0 + c4 * 4);
            As[c4*4+0][r] = g.x; As[c4*4+1][r] = g.y; As[c4*4+2][r] = g.z; As[c4*4+3][r] = g.w;
        }
        {
            int kk = tid >> 4, c4 = tid & 15;
            float4 g = *reinterpret_cast<const float4*>(vn + (size_t)(k0 + kk) * ZDIM + c0 + c4 * 4);
            *reinterpret_cast<float4*>(&Bs[kk][c4 * 4]) = g;
        }
        __syncthreads();
#pragma unroll
        for (int kk = 0; kk < 16; ++kk) {
            float4 a4 = *reinterpret_cast<const float4*>(&As[kk][ty * 4]);
            float4 b4 = *reinterpret_cast<const float4*>(&Bs[kk][tx * 4]);
            float av[4] = {a4.x, a4.y, a4.z, a4.w};
            float bv[4] = {b4.x, b4.y, b4.z, b4.w};
#pragma unroll
            for (int i = 0; i < 4; ++i)
#pragma unroll
                for (int j = 0; j < 4; ++j)
                    acc[i][j] = fmaf(av[i], bv[j], acc[i][j]);
        }
        __syncthreads();
    }
#pragma unroll
    for (int i = 0; i < 4; ++i) {
        int rg = r0 + ty * 4 + i;
#pragma unroll
        for (int j = 0; j < 4; ++j) {
            int cg = c0 + tx * 4 + j;
            Q[(size_t)rg * ZDIM + cg] = (rg == cg ? 1.0f : 0.0f) - 2.0f * acc[i][j];
        }
    }
}

// ---------------------------------------------------------------------------
// K3: A = Q @ r1 (natural [z][m]) and B1 = (Q @ r2^T)^T ([m][z]), both as
// split bf16 hi/lo. fp32 accumulate. Masks applied at load.
// ---------------------------------------------------------------------------
__global__ void __launch_bounds__(256) small_gemm_kernel(const float* __restrict__ Q,
                                                         const float* __restrict__ Rs,
                                                         const float* __restrict__ r2diag,
                                                         short* __restrict__ Ah_g,
                                                         short* __restrict__ Al_g,
                                                         short* __restrict__ B1h_g,
                                                         short* __restrict__ B1l_g) {
    int r0 = blockIdx.y * 64;
    int c0 = blockIdx.x * 64;
    int tid = threadIdx.x;
    int tx = tid & 15, ty = tid >> 4;

    __shared__ float Qs[16][68];
    __shared__ float RA[16][68];
    __shared__ float RB[16][68];

    float accA[4][4] = {};
    float accB[4][4] = {};

    for (int k0 = 0; k0 < ZDIM; k0 += 16) {
        {
            int r = tid >> 2, c4 = tid & 3;
            float4 g = *reinterpret_cast<const float4*>(Q + (size_t)(r0 + r) * ZDIM + k0 + c4 * 4);
            Qs[c4*4+0][r] = g.x; Qs[c4*4+1][r] = g.y; Qs[c4*4+2][r] = g.z; Qs[c4*4+3][r] = g.w;
        }
        {
            int kk = tid >> 4, c4 = tid & 15;
            int kg = k0 + kk, cg = c0 + c4 * 4;
            float4 g = *reinterpret_cast<const float4*>(Rs + (size_t)kg * MDIM + cg);
            float4 m;
            m.x = (kg <= cg + 0) ? g.x : 0.0f;
            m.y = (kg <= cg + 1) ? g.y : 0.0f;
            m.z = (kg <= cg + 2) ? g.z : 0.0f;
            m.w = (kg <= cg + 3) ? g.w : 0.0f;
            *reinterpret_cast<float4*>(&RA[kk][c4 * 4]) = m;
        }
        {
            int c = tid >> 2, k4 = tid & 3;
            int cg = c0 + c;
            float4 g = *reinterpret_cast<const float4*>(Rs + (size_t)cg * MDIM + k0 + k4 * 4);
            float gv[4] = {g.x, g.y, g.z, g.w};
#pragma unroll
            for (int qq = 0; qq < 4; ++qq) {
                int kg = k0 + k4 * 4 + qq;
                float val = (kg > cg) ? gv[qq] : ((kg == cg) ? r2diag[cg] : 0.0f);
                RB[k4 * 4 + qq][c] = val;
            }
        }
        __syncthreads();
#pragma unroll
        for (int kk = 0; kk < 16; ++kk) {
            float4 aq = *reinterpret_cast<const float4*>(&Qs[kk][ty * 4]);
            float4 ra = *reinterpret_cast<const float4*>(&RA[kk][tx * 4]);
            float4 rb = *reinterpret_cast<const float4*>(&RB[kk][tx * 4]);
            float av[4]  = {aq.x, aq.y, aq.z, aq.w};
            float rav[4] = {ra.x, ra.y, ra.z, ra.w};
            float rbv[4] = {rb.x, rb.y, rb.z, rb.w};
#pragma unroll
            for (int i = 0; i < 4; ++i)
#pragma unroll
                for (int j = 0; j < 4; ++j) {
                    accA[i][j] = fmaf(av[i], rav[j], accA[i][j]);
                    accB[i][j] = fmaf(av[i], rbv[j], accB[i][j]);
                }
        }
        __syncthreads();
    }
#pragma unroll
    for (int i = 0; i < 4; ++i) {
        int rg = r0 + ty * 4 + i;  // z index
#pragma unroll
        for (int j = 0; j < 4; ++j) {
            int cg = c0 + tx * 4 + j;  // m index
            short h, l;
            split2(accA[i][j], h, l);
            Ah_g[(size_t)rg * MDIM + cg] = h;
            Al_g[(size_t)rg * MDIM + cg] = l;
            split2(accB[i][j], h, l);
            B1h_g[(size_t)cg * ZDIM + rg] = h;
            B1l_g[(size_t)cg * ZDIM + rg] = l;
        }
    }
}

// ---------------------------------------------------------------------------
// K4: gemm1 MFMA split-3 (round-3 structure): Btzc = z @ Bt + c; hB = tanh ->
// packed (hi|lo<<16) u32 into d_out; ldj fused. Tile 128x256, 4 waves, BK=32.
// ---------------------------------------------------------------------------
__global__ void __launch_bounds__(256, 2) gemm1_mfma(const float* __restrict__ z,
                                                     const short* __restrict__ B1h,
                                                     const short* __restrict__ B1l,
                                                     const float* __restrict__ cvec,
                                                     const float* __restrict__ rrii,
                                                     uint32_t* __restrict__ hBp,
                                                     float* __restrict__ ldj) {
    int b0 = blockIdx.x * 128;
    int c0 = blockIdx.y * 256;
    int tid = threadIdx.x;

    __shared__ short Azh[128][40], Azl[128][40];
    __shared__ short Bsh[256][40], Bsl[256][40];

    int wid = tid >> 6, lane = tid & 63;
    int wm = wid >> 1, wn = wid & 1;          // wave grid 2x2
    int lrow = lane & 15, lk = (lane >> 4) * 8;

    f32x4 acc[4][8];
#pragma unroll
    for (int m = 0; m < 4; ++m)
#pragma unroll
        for (int n = 0; n < 8; ++n) acc[m][n] = (f32x4){0.f, 0.f, 0.f, 0.f};

    for (int k0 = 0; k0 < ZDIM; k0 += 32) {
        {   // stage z tile [128][32] -> hi/lo bf16
            int r = tid >> 1, half = tid & 1;
            const float* zp = z + (size_t)(b0 + r) * ZDIM + k0 + half * 16;
            float xv[16];
            *reinterpret_cast<float4*>(&xv[0])  = *reinterpret_cast<const float4*>(zp);
            *reinterpret_cast<float4*>(&xv[4])  = *reinterpret_cast<const float4*>(zp + 4);
            *reinterpret_cast<float4*>(&xv[8])  = *reinterpret_cast<const float4*>(zp + 8);
            *reinterpret_cast<float4*>(&xv[12]) = *reinterpret_cast<const float4*>(zp + 12);
            s16x8 h0, h1, l0, l1;
#pragma unroll
            for (int j = 0; j < 8; ++j) { short hh, ll; split2(xv[j],     hh, ll); h0[j] = hh; l0[j] = ll; }
#pragma unroll
            for (int j = 0; j < 8; ++j) { short hh, ll; split2(xv[8 + j], hh, ll); h1[j] = hh; l1[j] = ll; }
            *reinterpret_cast<s16x8*>(&Azh[r][half * 16])     = h0;
            *reinterpret_cast<s16x8*>(&Azh[r][half * 16 + 8]) = h1;
            *reinterpret_cast<s16x8*>(&Azl[r][half * 16])     = l0;
            *reinterpret_cast<s16x8*>(&Azl[r][half * 16 + 8]) = l1;
        }
        {   // stage B1 tile [256][32] (already split bf16)
            const short* ph = B1h + (size_t)(c0 + tid) * ZDIM + k0;
            const short* pl = B1l + (size_t)(c0 + tid) * ZDIM + k0;
#pragma unroll
            for (int s = 0; s < 4; ++s)
                *reinterpret_cast<s16x8*>(&Bsh[tid][s * 8]) = *reinterpret_cast<const s16x8*>(ph + s * 8);
#pragma unroll
            for (int s = 0; s < 4; ++s)
                *reinterpret_cast<s16x8*>(&Bsl[tid][s * 8]) = *reinterpret_cast<const s16x8*>(pl + s * 8);
        }
        __syncthreads();

        s16x8 ah[4], al[4];
#pragma unroll
        for (int m = 0; m < 4; ++m) {
            ah[m] = *reinterpret_cast<const s16x8*>(&Azh[wm * 64 + m * 16 + lrow][lk]);
            al[m] = *reinterpret_cast<const s16x8*>(&Azl[wm * 64 + m * 16 + lrow][lk]);
        }
#pragma unroll
        for (int n = 0; n < 8; ++n) {
            s16x8 bh = *reinterpret_cast<const s16x8*>(&Bsh[wn * 128 + n * 16 + lrow][lk]);
            s16x8 bl = *reinterpret_cast<const s16x8*>(&Bsl[wn * 128 + n * 16 + lrow][lk]);
#pragma unroll
            for (int m = 0; m < 4; ++m) {
                acc[m][n] = __builtin_amdgcn_mfma_f32_16x16x32_bf16(ah[m], bh, acc[m][n], 0, 0, 0);
                acc[m][n] = __builtin_amdgcn_mfma_f32_16x16x32_bf16(al[m], bh, acc[m][n], 0, 0, 0);
                acc[m][n] = __builtin_amdgcn_mfma_f32_16x16x32_bf16(ah[m], bl, acc[m][n], 0, 0, 0);
            }
        }
        __syncthreads();
    }

    float cv[8], rr[8];
#pragma unroll
    for (int n = 0; n < 8; ++n) {
        int col = c0 + wn * 128 + n * 16 + lrow;
        cv[n] = cvec[col];
        rr[n] = rrii[col];
    }
    float lsum[4][4];
#pragma unroll
    for (int m = 0; m < 4; ++m)
#pragma unroll
        for (int r = 0; r < 4; ++r) lsum[m][r] = 0.0f;

#pragma unroll
    for (int m = 0; m < 4; ++m) {
#pragma unroll
        for (int r = 0; r < 4; ++r) {
            int b = b0 + wm * 64 + m * 16 + (lane >> 4) * 4 + r;
#pragma unroll
            for (int n = 0; n < 8; ++n) {
                float val = acc[m][n][r] + cv[n];
                float h = tanhf(val);
                short hh, ll;
                split2(h, hh, ll);
                int col = c0 + wn * 128 + n * 16 + lrow;
                hBp[(size_t)b * MDIM + col] = (uint32_t)(uint16_t)hh | ((uint32_t)(uint16_t)ll << 16);
                float der = 1.0f - h * h;
                lsum[m][r] += logf(fabsf(fmaf(der, rr[n], 1.0f)));
            }
        }
    }
#pragma unroll
    for (int m = 0; m < 4; ++m) {
#pragma unroll
        for (int r = 0; r < 4; ++r) {
            float s = lsum[m][r];
            s += __shfl_xor(s, 1, 64);
            s += __shfl_xor(s, 2, 64);
            s += __shfl_xor(s, 4, 64);
            s += __shfl_xor(s, 8, 64);
            if ((lane & 15) == 0)
                atomicAdd(&ldj[b0 + wm * 64 + m * 16 + (lane >> 4) * 4 + r], s);
        }
    }
}

// ---------------------------------------------------------------------------
// K5: gemm2 MFMA split-3 (round-3 structure), IN-PLACE over packed hB in
// d_out. Tile 128x512 (full N -> block owns its rows), 8 waves, BK=32.
// ---------------------------------------------------------------------------
__global__ void __launch_bounds__(512, 2) gemm2_mfma(const float* __restrict__ z,
                                                     const short* __restrict__ Ah_g,
                                                     const short* __restrict__ Al_g,
                                                     float* __restrict__ out) {
    int b0 = blockIdx.x * 128;
    int tid = threadIdx.x;
    const uint32_t* hBp = reinterpret_cast<const uint32_t*>(out);

    __shared__ short Hh[128][40], Hl[128][40];
    __shared__ short Ash[512][40], Asl[512][40];

    int wid = tid >> 6, lane = tid & 63;
    int wm = wid >> 2, wn = wid & 3;          // wave grid 2x4
    int lrow = lane & 15, lk = (lane >> 4) * 8;

    f32x4 acc[4][8];
#pragma unroll
    for (int m = 0; m < 4; ++m)
#pragma unroll
        for (int n = 0; n < 8; ++n) acc[m][n] = (f32x4){0.f, 0.f, 0.f, 0.f};

    for (int m0 = 0; m0 < MDIM; m0 += 32) {
        {   // stage hB tile [128][32] u32 -> unpack hi/lo
            int r = tid >> 2, q = tid & 3;
            const uint32_t* hp = hBp + (size_t)(b0 + r) * MDIM + m0 + q * 8;
            uint4 u0 = *reinterpret_cast<const uint4*>(hp);
            uint4 u1 = *reinterpret_cast<const uint4*>(hp + 4);
            uint32_t uv[8] = {u0.x, u0.y, u0.z, u0.w, u1.x, u1.y, u1.z, u1.w};
            s16x8 vh, vl;
#pragma unroll
            for (int j = 0; j < 8; ++j) {
                vh[j] = (short)(uv[j] & 0xffffu);
                vl[j] = (short)(uv[j] >> 16);
            }
            *reinterpret_cast<s16x8*>(&Hh[r][q * 8]) = vh;
            *reinterpret_cast<s16x8*>(&Hl[r][q * 8]) = vl;
        }
        {   // stage A tile [512][32], already split bf16
            const short* ph = Ah_g + (size_t)tid * MDIM + m0;
            const short* pl = Al_g + (size_t)tid * MDIM + m0;
#pragma unroll
            for (int s = 0; s < 4; ++s)
                *reinterpret_cast<s16x8*>(&Ash[tid][s * 8]) = *reinterpret_cast<const s16x8*>(ph + s * 8);
#pragma unroll
            for (int s = 0; s < 4; ++s)
                *reinterpret_cast<s16x8*>(&Asl[tid][s * 8]) = *reinterpret_cast<const s16x8*>(pl + s * 8);
        }
        __syncthreads();

        s16x8 ah[4], al[4];
#pragma unroll
        for (int m = 0; m < 4; ++m) {
            ah[m] = *reinterpret_cast<const s16x8*>(&Hh[wm * 64 + m * 16 + lrow][lk]);
            al[m] = *reinterpret_cast<const s16x8*>(&Hl[wm * 64 + m * 16 + lrow][lk]);
        }
#pragma unroll
        for (int n = 0; n < 8; ++n) {
            s16x8 bh = *reinterpret_cast<const s16x8*>(&Ash[wn * 128 + n * 16 + lrow][lk]);
            s16x8 bl = *reinterpret_cast<const s16x8*>(&Asl[wn * 128 + n * 16 + lrow][lk]);
#pragma unroll
            for (int m = 0; m < 4; ++m) {
                acc[m][n] = __builtin_amdgcn_mfma_f32_16x16x32_bf16(ah[m], bh, acc[m][n], 0, 0, 0);
                acc[m][n] = __builtin_amdgcn_mfma_f32_16x16x32_bf16(al[m], bh, acc[m][n], 0, 0, 0);
                acc[m][n] = __builtin_amdgcn_mfma_f32_16x16x32_bf16(ah[m], bl, acc[m][n], 0, 0, 0);
            }
        }
        __syncthreads();
    }

#pragma unroll
    for (int m = 0; m < 4; ++m) {
#pragma unroll
        for (int r = 0; r < 4; ++r) {
            int b = b0 + wm * 64 + m * 16 + (lane >> 4) * 4 + r;
#pragma unroll
            for (int n = 0; n < 8; ++n) {
                int colz = wn * 128 + n * 16 + lrow;
                out[(size_t)b * ZDIM + colz] = acc[m][n][r] + z[(size_t)b * ZDIM + colz];
            }
        }
    }
}

// ---------------------------------------------------------------------------
extern "C" void kernel_launch(void* const* d_in, const int* in_sizes, int n_in,
                              void* d_out, int out_size, void* d_ws, size_t ws_size,
                              hipStream_t stream) {
    const float* z      = (const float*)d_in[0];
    const float* v      = (const float*)d_in[1];
    const float* Rs     = (const float*)d_in[2];
    const float* r2diag = (const float*)d_in[3];
    const float* cvec   = (const float*)d_in[4];

    float* out = (float*)d_out;
    float* ldj = out + (size_t)NBATCH * ZDIM;

    float* ws   = (float*)d_ws;            // ~6.3 MB used
    float* vn   = ws;                      // 512*512 f32 (row 511 zeroed)
    float* Q    = ws + 262144;             // 512*512 f32
    float* G    = ws + 2 * 262144;         // 512*512 f32 Gram
    float* D    = ws + 3 * 262144;         // 512*512 f32 trisolve solution
    float* rrii = ws + 4 * 262144;         // 512 f32
    short* sbase = (short*)(ws + 4 * 262144 + 512);
    short* Ah_g = sbase;                   // A hi, natural [z][m]
    short* Al_g = sbase + 262144;
    short* B1h  = sbase + 2 * 262144;      // B1 = Bt^T hi, [m][z]
    short* B1l  = sbase + 3 * 262144;

    hipMemsetAsync(ldj, 0, NBATCH * sizeof(float), stream);

    prep_kernel<<<512, 64, 0, stream>>>(v, Rs, r2diag, vn, rrii);
    gram_kernel<<<dim3(8, 8), 256, 0, stream>>>(vn, G);
    for (int b = 0; b < 8; ++b) {
        partial_kernel<<<8, 256, 0, stream>>>(D, G, vn, b);
        trisolve_kernel<<<1, 512, 0, stream>>>(D, G, b);
    }
    qbuild_kernel<<<dim3(8, 8), 256, 0, stream>>>(D, vn, Q);
    small_gemm_kernel<<<dim3(8, 8), 256, 0, stream>>>(Q, Rs, r2diag, Ah_g, Al_g, B1h, B1l);
    gemm1_mfma<<<dim3(512, 2), 256, 0, stream>>>(z, B1h, B1l, cvec, rrii, (uint32_t*)out, ldj);
    gemm2_mfma<<<512, 512, 0, stream>>>(z, Ah_g, Al_g, out);
}